// Round 1
// baseline (762.007 us; speedup 1.0000x reference)
//
#include <hip/hip_runtime.h>
#include <math.h>

#define N_DIM 32
#define C_DIM 512
#define K_DIM 64
#define P_DIM 3136
#define PHALF 1568   // P_DIM / 2
#define CT 64        // c-tile in gemm2
#define KT 64        // k-tile in gemm2 (== K_DIM)
#define PC 32        // p-chunk staged in LDS

// ---------------- prep: transpose conv_w -> wt[c][k], zero gsum ----------------
__global__ __launch_bounds__(256) void k_prep(const float* __restrict__ conv_w,
                                              float* __restrict__ wt,
                                              float* __restrict__ gsum) {
    int idx = blockIdx.x * 256 + threadIdx.x;   // 0 .. 32767
    int c = idx >> 6;
    int k = idx & 63;
    wt[idx] = conv_w[k * C_DIM + c];
    if (idx < N_DIM) gsum[idx] = 0.0f;
}

// ---------------- GEMM1 + softmax: a[n][k][p] ----------------
// one thread per pixel; 64 logit accumulators in registers.
__global__ __launch_bounds__(256) void k_logits(const float* __restrict__ x,
                                                const float* __restrict__ wt,
                                                const float* __restrict__ bias,
                                                float* __restrict__ a) {
    const int n = blockIdx.y;
    const int p = blockIdx.x * 256 + threadIdx.x;
    const bool valid = (p < P_DIM);
    const int pp = valid ? p : (P_DIM - 1);

    float logits[K_DIM];
#pragma unroll
    for (int k = 0; k < K_DIM; ++k) logits[k] = bias[k];

    const float* xn = x + (size_t)n * C_DIM * P_DIM + pp;

    float xv = xn[0];
    for (int c = 0; c < C_DIM; ++c) {
        // prefetch next x value so the load issues before the FMA burst
        float xnext = (c + 1 < C_DIM) ? xn[(size_t)(c + 1) * P_DIM] : 0.0f;
        const float4* w4 = (const float4*)(wt + c * K_DIM);  // wave-uniform row
#pragma unroll
        for (int q = 0; q < 16; ++q) {
            float4 w = w4[q];
            logits[4 * q + 0] = fmaf(xv, w.x, logits[4 * q + 0]);
            logits[4 * q + 1] = fmaf(xv, w.y, logits[4 * q + 1]);
            logits[4 * q + 2] = fmaf(xv, w.z, logits[4 * q + 2]);
            logits[4 * q + 3] = fmaf(xv, w.w, logits[4 * q + 3]);
        }
        xv = xnext;
    }

    // softmax over k
    float m = logits[0];
#pragma unroll
    for (int k = 1; k < K_DIM; ++k) m = fmaxf(m, logits[k]);
    float s = 0.0f;
#pragma unroll
    for (int k = 0; k < K_DIM; ++k) {
        float e = __expf(logits[k] - m);
        logits[k] = e;
        s += e;
    }
    const float inv = 1.0f / s;

    if (valid) {
        float* ap = a + (size_t)n * K_DIM * P_DIM + p;
#pragma unroll
        for (int k = 0; k < K_DIM; ++k) ap[(size_t)k * P_DIM] = logits[k] * inv;
    }
}

// ---------------- asum[n][k] = sum_p a[n][k][p] ----------------
__global__ __launch_bounds__(256) void k_asum(const float* __restrict__ a,
                                              float* __restrict__ asum) {
    const int nk = blockIdx.x;  // 0 .. N*K-1
    const float* ap = a + (size_t)nk * P_DIM;
    float s = 0.0f;
    for (int i = threadIdx.x; i < P_DIM; i += 256) s += ap[i];
    __shared__ float red[256];
    red[threadIdx.x] = s;
    __syncthreads();
    for (int o = 128; o > 0; o >>= 1) {
        if (threadIdx.x < o) red[threadIdx.x] += red[threadIdx.x + o];
        __syncthreads();
    }
    if (threadIdx.x == 0) asum[nk] = red[0];
}

// ---------------- GEMM2: part[s][n][c][k] = sum_{p in slice s} x[n][c][p]*a[n][k][p] ----
__global__ __launch_bounds__(256) void k_gemm2(const float* __restrict__ x,
                                               const float* __restrict__ a,
                                               float* __restrict__ part) {
    __shared__ float xs[PC][CT + 4];
    __shared__ float as[PC][KT + 4];

    const int ct = blockIdx.x;   // 0..7
    const int n  = blockIdx.y;   // 0..31
    const int s  = blockIdx.z;   // 0..1

    const int tid = threadIdx.x;
    const int tc = tid >> 4;     // 0..15
    const int tk = tid & 15;     // 0..15

    // staging mapping: 64 channels x (4 groups of 8 p)
    const int lc = tid >> 2;         // 0..63
    const int lp = (tid & 3) * 8;    // 0,8,16,24

    float acc[4][4];
#pragma unroll
    for (int i = 0; i < 4; ++i)
#pragma unroll
        for (int j = 0; j < 4; ++j) acc[i][j] = 0.0f;

    const float* xb = x + (size_t)n * C_DIM * P_DIM + (size_t)(ct * CT) * P_DIM;
    const float* ab = a + (size_t)n * K_DIM * P_DIM;
    const int p0 = s * PHALF;

    for (int pb = p0; pb < p0 + PHALF; pb += PC) {
        const float* gx = xb + (size_t)lc * P_DIM + pb + lp;
        float4 v0 = *(const float4*)(gx);
        float4 v1 = *(const float4*)(gx + 4);
        const float* ga = ab + (size_t)lc * P_DIM + pb + lp;
        float4 u0 = *(const float4*)(ga);
        float4 u1 = *(const float4*)(ga + 4);

        xs[lp + 0][lc] = v0.x; xs[lp + 1][lc] = v0.y;
        xs[lp + 2][lc] = v0.z; xs[lp + 3][lc] = v0.w;
        xs[lp + 4][lc] = v1.x; xs[lp + 5][lc] = v1.y;
        xs[lp + 6][lc] = v1.z; xs[lp + 7][lc] = v1.w;
        as[lp + 0][lc] = u0.x; as[lp + 1][lc] = u0.y;
        as[lp + 2][lc] = u0.z; as[lp + 3][lc] = u0.w;
        as[lp + 4][lc] = u1.x; as[lp + 5][lc] = u1.y;
        as[lp + 6][lc] = u1.z; as[lp + 7][lc] = u1.w;
        __syncthreads();

#pragma unroll
        for (int pp = 0; pp < PC; ++pp) {
            float4 xv = *(const float4*)&xs[pp][tc * 4];
            float4 av = *(const float4*)&as[pp][tk * 4];
            float xr[4] = {xv.x, xv.y, xv.z, xv.w};
            float ar[4] = {av.x, av.y, av.z, av.w};
#pragma unroll
            for (int i = 0; i < 4; ++i)
#pragma unroll
                for (int j = 0; j < 4; ++j)
                    acc[i][j] = fmaf(xr[i], ar[j], acc[i][j]);
        }
        __syncthreads();
    }

    float* po = part + ((size_t)s * N_DIM + n) * (size_t)C_DIM * K_DIM +
                (size_t)(ct * CT) * K_DIM;
#pragma unroll
    for (int i = 0; i < 4; ++i) {
        float4 o;
        o.x = acc[i][0]; o.y = acc[i][1]; o.z = acc[i][2]; o.w = acc[i][3];
        *(float4*)&po[(size_t)(tc * 4 + i) * K_DIM + tk * 4] = o;
    }
}

// ---------------- intra-norm over k + accumulate global sumsq ----------------
__global__ __launch_bounds__(256) void k_intra(const float* __restrict__ part,
                                               const float* __restrict__ cent,
                                               const float* __restrict__ asum,
                                               float* __restrict__ out,
                                               float* __restrict__ gsum) {
    const int w = (blockIdx.x * 256 + threadIdx.x) >> 6;  // (n,c) wave id
    const int lane = threadIdx.x & 63;
    const int n = w >> 9;     // /512
    const int c = w & 511;
    const size_t off = ((size_t)n * C_DIM + c) * K_DIM + lane;
    const size_t half = (size_t)N_DIM * C_DIM * K_DIM;

    // cent_r[c][k] = centroids_flat[c*64 + k]  (row-major reshape, NOT transpose)
    float v = part[off] + part[half + off] -
              cent[c * K_DIM + lane] * asum[n * K_DIM + lane];

    float ss = v * v;
#pragma unroll
    for (int o = 32; o > 0; o >>= 1) ss += __shfl_xor(ss, o);

    const float norm = sqrtf(ss);
    const float denom = fmaxf(norm, 1e-12f);
    const float vn = v / denom;
    out[off] = vn;
    if (lane == 0) atomicAdd(&gsum[n], ss / (denom * denom));
}

// ---------------- final global L2 normalization ----------------
__global__ __launch_bounds__(256) void k_final(float* __restrict__ out,
                                               const float* __restrict__ gsum) {
    const size_t i = (size_t)blockIdx.x * 256 + threadIdx.x;  // 0 .. 2^20-1
    const int n = (int)(i >> 15);                             // C*K = 32768
    const float g = sqrtf(gsum[n]);
    out[i] = out[i] / fmaxf(g, 1e-12f);
}

extern "C" void kernel_launch(void* const* d_in, const int* in_sizes, int n_in,
                              void* d_out, int out_size, void* d_ws, size_t ws_size,
                              hipStream_t stream) {
    const float* x      = (const float*)d_in[0];  // (32,512,56,56)
    const float* cent   = (const float*)d_in[1];  // (64,512) flat
    const float* conv_w = (const float*)d_in[2];  // (64,512)
    const float* conv_b = (const float*)d_in[3];  // (64,)

    float* ws   = (float*)d_ws;
    float* wt   = ws;                              // 32768
    float* a    = wt + 32768;                      // 32*64*3136 = 6422528
    float* asum = a + (size_t)N_DIM * K_DIM * P_DIM;  // 2048
    float* part = asum + N_DIM * K_DIM;            // 2 * 1048576
    float* gsum = part + 2 * (size_t)N_DIM * C_DIM * K_DIM;  // 32
    float* out  = (float*)d_out;

    hipLaunchKernelGGL(k_prep,   dim3(128),       dim3(256), 0, stream, conv_w, wt, gsum);
    hipLaunchKernelGGL(k_logits, dim3(13, 32),    dim3(256), 0, stream, x, wt, conv_b, a);
    hipLaunchKernelGGL(k_asum,   dim3(2048),      dim3(256), 0, stream, a, asum);
    hipLaunchKernelGGL(k_gemm2,  dim3(8, 32, 2),  dim3(256), 0, stream, x, a, part);
    hipLaunchKernelGGL(k_intra,  dim3(4096),      dim3(256), 0, stream, part, cent, asum, out, gsum);
    hipLaunchKernelGGL(k_final,  dim3(4096),      dim3(256), 0, stream, out, gsum);
}